// Round 8
// baseline (24.277 us; speedup 1.0000x reference)
//
#include <hip/hip_runtime.h>

// x: [2,2,8,64,64,64] fp32 0/1 -> 2048 images of 64x64.
// Per image: #4-connected components; per group of 64 images: sum // 64 -> float.
//
// One 256-thread block per image; thread = 4*row + quarter. Threads build row
// masks in registers (16 px/thread, width-4 shuffle butterfly). Horizontal
// runs are free (bitmask). Union-find over runs (id = row*32+rank) in an 8 KB
// LDS table with atomicMin hooking (R6 semantics). NEW vs R6: per-thread
// BATCHED finds — up to 4 segments' (a,b) walk pointers advance in lock-step
// sweeps (8 independent LDS loads in flight), so find latency ~= one chain
// instead of the sum of chains; hooks then run through the proven merge()
// whose internal finds are O(1). Batch phase does no writes -> semantics
// identical to R6. components = total_runs - root_kills.
constexpr int NPIX = 64 * 64;
constexpr int PATCHES = 64;
constexpr int RUNS_PER_ROW = 32;
constexpr int TABLE = 64 * RUNS_PER_ROW;  // 2048 run slots

// Find with path halving (benign race: only ever points i to an ancestor).
__device__ __forceinline__ int find_root(volatile int* p, int i) {
    while (true) {
        int pi = p[i];
        if (pi == i) return i;
        int gp = p[pi];
        if (gp == pi) return pi;
        p[i] = gp;
        i = gp;
    }
}

// Priority union via atomicMin hooking. Returns 1 iff this call killed a
// root (p[b] transitions b -> smaller exactly once, seen by a unique thread).
__device__ __forceinline__ int merge(int* p, int a, int b) {
    while (true) {
        a = find_root(p, a);
        b = find_root(p, b);
        if (a == b) return 0;
        if (a > b) { int t = a; a = b; b = t; }  // a < b
        int old = atomicMin(&p[b], a);
        if (old == b) return 1;  // we killed root b
        b = old;                 // p[b] was already smaller; chase it
    }
}

__global__ __launch_bounds__(256, 8) void cc_kernel(const float* __restrict__ in,
                                                    int* __restrict__ counts) {
    __shared__ int par[TABLE];               // 8 KB
    __shared__ unsigned long long mrow[64];  // row masks
    __shared__ int wpart[4];
    const int tid = threadIdx.x;
    const int img = blockIdx.x;
    const int r = tid >> 2;  // row 0..63
    const int q = tid & 3;   // quarter 0..3

    // ---- load 16 consecutive pixels (4 x float4 = one 64B line) ----
    const float4* src =
        reinterpret_cast<const float4*>(in + (size_t)img * NPIX + r * 64 + q * 16);
    float4 buf[4];
#pragma unroll
    for (int k = 0; k < 4; ++k) buf[k] = src[k];

    // ---- identity-init run table while loads are in flight ----
    {
        int b0 = tid * 4;
        *reinterpret_cast<int4*>(&par[b0]) = make_int4(b0, b0 + 1, b0 + 2, b0 + 3);
        int b1 = 1024 + tid * 4;
        *reinterpret_cast<int4*>(&par[b1]) = make_int4(b1, b1 + 1, b1 + 2, b1 + 3);
    }

    // ---- 16-bit quarter mask, then full row mask via width-4 butterfly ----
    unsigned qm = 0;
#pragma unroll
    for (int k = 0; k < 4; ++k) {
        qm |= (buf[k].x > 0.5f ? 1u : 0u) << (4 * k);
        qm |= (buf[k].y > 0.5f ? 2u : 0u) << (4 * k);
        qm |= (buf[k].z > 0.5f ? 4u : 0u) << (4 * k);
        qm |= (buf[k].w > 0.5f ? 8u : 0u) << (4 * k);
    }
    unsigned long long m = (unsigned long long)qm << (16 * q);
    m |= __shfl_xor(m, 1, 4);
    m |= __shfl_xor(m, 2, 4);  // all 4 threads of row r hold the full mask

    if (q == 0) mrow[r] = m;
    __syncthreads();  // par + mrow visible

    const unsigned long long ma = m;
    const unsigned long long mb = (r < 63) ? mrow[r + 1] : 0ull;
    const unsigned long long sa = ma & ~(ma << 1);
    const unsigned long long sb = mb & ~(mb << 1);
    const unsigned long long qmask = 0xFFFFull << (16 * q);

    int cnt = __popcll(sa & qmask);  // run starts partitioned by quarter

    // ---- unions: overlap segments starting in this quarter, batched 4 ----
    unsigned long long both = ma & mb;
    unsigned long long ov = (both & ~(both << 1)) & qmask;  // <= 8 segments

    volatile int* vpar = par;
    for (int pass = 0; pass < 2; ++pass) {  // 2nd pass only if >4 segments
        if (!ov && pass) break;
        int raA[4], rbA[4];
        // extract up to 4 segments; unused slots -> node 0 (always a root)
#pragma unroll
        for (int j = 0; j < 4; ++j) {
            raA[j] = 0;
            rbA[j] = 0;
            if (ov) {
                int x = __builtin_ctzll(ov);
                ov &= ov - 1;
                unsigned long long below = (2ull << x) - 1;  // bits 0..x
                raA[j] = r * RUNS_PER_ROW + __popcll(sa & below) - 1;
                rbA[j] = (r + 1) * RUNS_PER_ROW + __popcll(sb & below) - 1;
            }
        }
        // batched lock-step walk: 8 independent LDS loads per sweep
        bool more = true;
        while (more) {
            more = false;
#pragma unroll
            for (int j = 0; j < 4; ++j) {
                int pa = vpar[raA[j]];
                int pb = vpar[rbA[j]];
                if (pa != raA[j]) { raA[j] = pa; more = true; }
                if (pb != rbA[j]) { rbA[j] = pb; more = true; }
            }
        }
        // hooks: internal finds are O(1) now; counting semantics unchanged
#pragma unroll
        for (int j = 0; j < 4; ++j) {
            if (raA[j] != rbA[j]) cnt -= merge(par, raA[j], rbA[j]);
        }
    }

    // ---- block reduction of (runs - kills); plain store ----
#pragma unroll
    for (int d = 32; d > 0; d >>= 1) cnt += __shfl_xor(cnt, d, 64);
    if ((tid & 63) == 0) wpart[tid >> 6] = cnt;
    __syncthreads();
    if (tid == 0) counts[img] = wpart[0] + wpart[1] + wpart[2] + wpart[3];
}

// One block: group g = 8 threads summing its 64 per-image counts.
__global__ void finalize_kernel(const int* __restrict__ counts,
                                float* __restrict__ out, int ngroups) {
    const int t = threadIdx.x;
    const int g = t >> 3, j = t & 7;
    if (g >= ngroups) return;
    const int* c = counts + g * PATCHES + j * 8;
    int s = 0;
#pragma unroll
    for (int k = 0; k < 8; ++k) s += c[k];
#pragma unroll
    for (int d = 4; d > 0; d >>= 1) s += __shfl_down(s, d, 8);
    if (j == 0) out[g] = (float)(s >> 6);  // sum // 64 (sum >= 0)
}

extern "C" void kernel_launch(void* const* d_in, const int* in_sizes, int n_in,
                              void* d_out, int out_size, void* d_ws, size_t ws_size,
                              hipStream_t stream) {
    const float* x = (const float*)d_in[0];
    float* out = (float*)d_out;
    int* counts = (int*)d_ws;

    const int nimg = in_sizes[0] / NPIX;  // 2048
    const int ngroups = out_size;         // 32

    cc_kernel<<<nimg, 256, 0, stream>>>(x, counts);
    finalize_kernel<<<1, ngroups * 8, 0, stream>>>(counts, out, ngroups);
}

// Round 9
// 22.967 us; speedup vs baseline: 1.0570x; 1.0570x over previous
//
#include <hip/hip_runtime.h>

// x: [2,2,8,64,64,64] fp32 0/1 -> 2048 images of 64x64.
// Per image: #4-connected components; per group of 64 images: sum // 64 -> float.
//
// One 256-thread block per image. Loads are FULLY COALESCED: instruction k
// loads float4 #(k*256+tid) (lane-contiguous 16B, block-contiguous 4KB).
// Each thread's float4 is a 4-pixel nibble of row 16k+4w+(L>>4) at position
// L&15; a width-16 shfl_xor OR-butterfly assembles row masks, one writer per
// row stores to LDS. Union-find over runs (id = row*32+rank) in an 8 KB LDS
// table with atomicMin hooking (R6 semantics, R7/R8 experiments reverted).
// components = total_runs - root_kills; plain store + tiny reduce kernel.
constexpr int NPIX = 64 * 64;
constexpr int PATCHES = 64;
constexpr int RUNS_PER_ROW = 32;
constexpr int TABLE = 64 * RUNS_PER_ROW;  // 2048 run slots

// Find with path halving (benign race: only ever points i to an ancestor).
__device__ __forceinline__ int find_root(volatile int* p, int i) {
    while (true) {
        int pi = p[i];
        if (pi == i) return i;
        int gp = p[pi];
        if (gp == pi) return pi;
        p[i] = gp;
        i = gp;
    }
}

// Priority union via atomicMin hooking. Returns 1 iff this call killed a
// root (p[b] transitions b -> smaller exactly once, seen by a unique thread).
__device__ __forceinline__ int merge(int* p, int a, int b) {
    while (true) {
        a = find_root(p, a);
        b = find_root(p, b);
        if (a == b) return 0;
        if (a > b) { int t = a; a = b; b = t; }  // a < b
        int old = atomicMin(&p[b], a);
        if (old == b) return 1;  // we killed root b
        b = old;                 // p[b] was already smaller; chase it
    }
}

__global__ __launch_bounds__(256, 8) void cc_kernel(const float* __restrict__ in,
                                                    int* __restrict__ counts) {
    __shared__ int par[TABLE];               // 8 KB
    __shared__ unsigned long long mrow[64];  // row masks
    __shared__ int wpart[4];
    const int tid = threadIdx.x;
    const int img = blockIdx.x;

    // ---- coalesced loads: instruction k is lane-contiguous ----
    const float4* base = reinterpret_cast<const float4*>(in + (size_t)img * NPIX);
    float4 v[4];
#pragma unroll
    for (int k = 0; k < 4; ++k) v[k] = base[k * 256 + tid];

    // ---- identity-init run table while loads are in flight ----
    {
        int b0 = tid * 4;
        *reinterpret_cast<int4*>(&par[b0]) = make_int4(b0, b0 + 1, b0 + 2, b0 + 3);
        int b1 = 1024 + tid * 4;
        *reinterpret_cast<int4*>(&par[b1]) = make_int4(b1, b1 + 1, b1 + 2, b1 + 3);
    }

    // ---- nibble -> row-mask assembly via width-16 OR-butterfly ----
    // float4 #f (f = k*256+tid) covers pixels of row f>>4, cols (f&15)*4..+3.
    const int w = tid >> 6;    // wave
    const int L = tid & 63;    // lane
    const int bg = L >> 4;     // 16-lane group
    const int j = L & 15;      // nibble position in row
#pragma unroll
    for (int k = 0; k < 4; ++k) {
        unsigned nib = (v[k].x > 0.5f ? 1u : 0u) | (v[k].y > 0.5f ? 2u : 0u) |
                       (v[k].z > 0.5f ? 4u : 0u) | (v[k].w > 0.5f ? 8u : 0u);
        unsigned long long c = (unsigned long long)nib << (4 * j);
#pragma unroll
        for (int d = 1; d < 16; d <<= 1) c |= __shfl_xor(c, d, 16);
        if (j == 0) mrow[16 * k + 4 * w + bg] = c;  // row = f>>4
    }
    __syncthreads();  // par + mrow visible

    // ---- union phase: thread = 4*row + quarter (R6 unchanged) ----
    const int r = tid >> 2;  // row 0..63
    const int q = tid & 3;   // quarter 0..3
    const unsigned long long ma = mrow[r];
    const unsigned long long mb = (r < 63) ? mrow[r + 1] : 0ull;
    const unsigned long long sa = ma & ~(ma << 1);
    const unsigned long long sb = mb & ~(mb << 1);
    const unsigned long long qmask = 0xFFFFull << (16 * q);

    int cnt = __popcll(sa & qmask);  // run starts partitioned by quarter

    unsigned long long both = ma & mb;
    unsigned long long ov = (both & ~(both << 1)) & qmask;
    while (ov) {
        int x = __builtin_ctzll(ov);
        ov &= ov - 1;
        unsigned long long below = (2ull << x) - 1;  // bits 0..x
        int ida = r * RUNS_PER_ROW + __popcll(sa & below) - 1;
        int idb = (r + 1) * RUNS_PER_ROW + __popcll(sb & below) - 1;
        cnt -= merge(par, ida, idb);
    }

    // ---- block reduction of (runs - kills); plain store ----
#pragma unroll
    for (int d = 32; d > 0; d >>= 1) cnt += __shfl_xor(cnt, d, 64);
    if ((tid & 63) == 0) wpart[tid >> 6] = cnt;
    __syncthreads();
    if (tid == 0) counts[img] = wpart[0] + wpart[1] + wpart[2] + wpart[3];
}

// One block: group g = 8 threads summing its 64 per-image counts.
__global__ void finalize_kernel(const int* __restrict__ counts,
                                float* __restrict__ out, int ngroups) {
    const int t = threadIdx.x;
    const int g = t >> 3, j = t & 7;
    if (g >= ngroups) return;
    const int* c = counts + g * PATCHES + j * 8;
    int s = 0;
#pragma unroll
    for (int k = 0; k < 8; ++k) s += c[k];
#pragma unroll
    for (int d = 4; d > 0; d >>= 1) s += __shfl_down(s, d, 8);
    if (j == 0) out[g] = (float)(s >> 6);  // sum // 64 (sum >= 0)
}

extern "C" void kernel_launch(void* const* d_in, const int* in_sizes, int n_in,
                              void* d_out, int out_size, void* d_ws, size_t ws_size,
                              hipStream_t stream) {
    const float* x = (const float*)d_in[0];
    float* out = (float*)d_out;
    int* counts = (int*)d_ws;

    const int nimg = in_sizes[0] / NPIX;  // 2048
    const int ngroups = out_size;         // 32

    cc_kernel<<<nimg, 256, 0, stream>>>(x, counts);
    finalize_kernel<<<1, ngroups * 8, 0, stream>>>(counts, out, ngroups);
}